// Round 1
// baseline (2199.280 us; speedup 1.0000x reference)
//
#include <hip/hip_runtime.h>
#include <math.h>

// Problem constants (from reference): B=64, S=25, K=20, E=256, H=8
// D=512, L=501, hd=64, rows-per-batch N=500, total M rows = 32000.
#define BATCH 64
#define SLATES 25
#define KPS 20           // items per slate
#define EDIM 256
#define DDIM 512
#define HEADS 8
#define HD 64
#define LFULL 501
#define NROWS 500
#define MTOT (BATCH*NROWS)   // 32000

__device__ __forceinline__ float gelu_exact(float x) {
    return 0.5f * x * (1.0f + erff(x * 0.70710678118654752440f));
}

// ---------------------------------------------------------------------------
// Kernel 1: per-batch user-projection bias tables ub{q,k,v}[b,o] =
//   bias[o] + sum_e user[b,e] * W[o, 256+e]; also fill row 0 of q/k/v = bias.
// ---------------------------------------------------------------------------
__global__ __launch_bounds__(256) void user_bias_kernel(
    const float* __restrict__ user,
    const float* __restrict__ Wq, const float* __restrict__ bq,
    const float* __restrict__ Wk, const float* __restrict__ bk,
    const float* __restrict__ Wv, const float* __restrict__ bv,
    float* __restrict__ ubq, float* __restrict__ ubk, float* __restrict__ ubv,
    float* __restrict__ qb, float* __restrict__ kb, float* __restrict__ vb)
{
    const int b = blockIdx.x;
    const int tid = threadIdx.x;
    __shared__ float us[EDIM];
    if (tid < EDIM) us[tid] = user[b * EDIM + tid];
    __syncthreads();
    for (int o = tid; o < DDIM; o += 256) {
        float sq = bq[o], sk = bk[o], sv = bv[o];
        for (int e = 0; e < EDIM; ++e) {
            const float ue = us[e];
            sq += ue * Wq[(size_t)o * DDIM + EDIM + e];
            sk += ue * Wk[(size_t)o * DDIM + EDIM + e];
            sv += ue * Wv[(size_t)o * DDIM + EDIM + e];
        }
        ubq[b * DDIM + o] = sq;
        ubk[b * DDIM + o] = sk;
        ubv[b * DDIM + o] = sv;
        // row 0 of x is all zeros -> projections are the plain biases
        const size_t r0 = (size_t)b * LFULL * DDIM + o;
        qb[r0] = bq[o];
        kb[r0] = bk[o];
        vb[r0] = bv[o];
    }
}

// ---------------------------------------------------------------------------
// Generic fp32 GEMM: C = A(MxKdim) @ W(512xKdim, row-major, stride 512)^T
// 64x64 tile, BK=16, 256 threads, 4x4 microtile per thread.
// MODE 0: QKV  -> bias is per-batch table ub[B][512]; output scattered to
//                 (b,l,:) of a (B,501,512) buffer, l = m%500+1.
// MODE 1: plain bias, contiguous output m*512.
// MODE 2: plain bias + exact GELU, contiguous output.
// ---------------------------------------------------------------------------
template <int MODE>
__global__ __launch_bounds__(256) void gemm_kernel(
    const float* __restrict__ A, const float* __restrict__ W,
    const float* __restrict__ bias, float* __restrict__ C, int Kdim)
{
    const int tid = threadIdx.x;
    const int m0 = blockIdx.x * 64;
    const int n0 = blockIdx.y * 64;
    const int tx = tid & 15;       // 16 col groups
    const int ty = tid >> 4;       // 16 row groups

    __shared__ float As[16][64];
    __shared__ float Ws[16][64];

    float c[4][4] = {};

    const int lr  = tid >> 2;        // 0..63  row within tile to load
    const int lk0 = (tid & 3) * 4;   // 0,4,8,12

    for (int k0 = 0; k0 < Kdim; k0 += 16) {
        float4 a4 = *(const float4*)&A[(size_t)(m0 + lr) * Kdim + k0 + lk0];
        float4 w4 = *(const float4*)&W[(size_t)(n0 + lr) * DDIM + k0 + lk0];
        As[lk0 + 0][lr] = a4.x; As[lk0 + 1][lr] = a4.y;
        As[lk0 + 2][lr] = a4.z; As[lk0 + 3][lr] = a4.w;
        Ws[lk0 + 0][lr] = w4.x; Ws[lk0 + 1][lr] = w4.y;
        Ws[lk0 + 2][lr] = w4.z; Ws[lk0 + 3][lr] = w4.w;
        __syncthreads();
#pragma unroll
        for (int kk = 0; kk < 16; ++kk) {
            float4 a = *(const float4*)&As[kk][ty * 4];
            float4 w = *(const float4*)&Ws[kk][tx * 4];
            float ar[4] = {a.x, a.y, a.z, a.w};
            float wr[4] = {w.x, w.y, w.z, w.w};
#pragma unroll
            for (int i = 0; i < 4; ++i)
#pragma unroll
                for (int j = 0; j < 4; ++j) c[i][j] += ar[i] * wr[j];
        }
        __syncthreads();
    }

#pragma unroll
    for (int i = 0; i < 4; ++i) {
        const int m = m0 + ty * 4 + i;
        if (MODE == 0) {
            const int b = m / NROWS;
            const int l = m % NROWS + 1;
            const size_t base = ((size_t)b * LFULL + l) * DDIM + n0 + tx * 4;
            const float* u = &bias[(size_t)b * DDIM + n0 + tx * 4];
#pragma unroll
            for (int j = 0; j < 4; ++j) C[base + j] = c[i][j] + u[j];
        } else {
            const size_t base = (size_t)m * DDIM + n0 + tx * 4;
#pragma unroll
            for (int j = 0; j < 4; ++j) {
                float x = c[i][j] + bias[n0 + tx * 4 + j];
                if (MODE == 2) x = gelu_exact(x);
                C[base + j] = x;
            }
        }
    }
}

// ---------------------------------------------------------------------------
// Attention: one block per (slate, head, batch). Queries = the 20 rows of the
// slate (l = s0*20+1 .. s0*20+20). Allowed keys: k=0 plus clicked keys with
// k <= s0*20. Two-pass softmax with full score rows in LDS.
// Output written to compact (B, 500, 512) buffer (row l-1).
// ---------------------------------------------------------------------------
__global__ __launch_bounds__(256) void attn_kernel(
    const float* __restrict__ qx, const float* __restrict__ kx,
    const float* __restrict__ vx, const int* __restrict__ resp,
    float* __restrict__ out)
{
    const int s0 = blockIdx.x;   // 0..24
    const int h  = blockIdx.y;   // 0..7
    const int b  = blockIdx.z;   // 0..63
    const int tid = threadIdx.x;
    const int nk = s0 * KPS + 1; // keys 0..nk-1 (<= 481)

    __shared__ float qs[KPS][HD];        // 5 KB
    __shared__ float kv[64][65];         // 16.6 KB (padded: stride-64 -> conflict free)
    __shared__ float sc[KPS][481];       // 38.5 KB score rows

    // load the 20 query rows
    for (int idx = tid; idx < KPS * HD; idx += 256) {
        const int r = idx >> 6, d = idx & 63;
        qs[r][d] = qx[((size_t)b * LFULL + (s0 * KPS + 1 + r)) * DDIM + h * HD + d];
    }
    __syncthreads();

    // scores
    for (int k0 = 0; k0 < nk; k0 += 64) {
        const int tk = min(64, nk - k0);
        for (int idx = tid; idx < tk * HD; idx += 256) {
            const int kk = idx >> 6, d = idx & 63;
            kv[kk][d] = kx[((size_t)b * LFULL + (k0 + kk)) * DDIM + h * HD + d];
        }
        __syncthreads();
        for (int idx = tid; idx < KPS * 64; idx += 256) {
            const int r = idx >> 6, kk = idx & 63;
            if (kk < tk) {
                const int key = k0 + kk;
                const bool allow = (key == 0) || (resp[(size_t)b * NROWS + key - 1] > 0);
                float sv = -1e30f;
                if (allow) {
                    float acc = 0.f;
#pragma unroll
                    for (int d = 0; d < HD; ++d) acc += qs[r][d] * kv[kk][d];
                    sv = acc * 0.125f;  // 1/sqrt(64)
                }
                sc[r][key] = sv;
            }
        }
        __syncthreads();
    }

    // softmax: one wave per row, rows strided by 4 waves
    const int w = tid >> 6, lane = tid & 63;
    for (int r = w; r < KPS; r += 4) {
        float mx = -1e30f;
        for (int k_ = lane; k_ < nk; k_ += 64) mx = fmaxf(mx, sc[r][k_]);
#pragma unroll
        for (int off = 32; off; off >>= 1) mx = fmaxf(mx, __shfl_xor(mx, off, 64));
        float ss = 0.f;
        for (int k_ = lane; k_ < nk; k_ += 64) {
            const float p = expf(sc[r][k_] - mx);
            sc[r][k_] = p;
            ss += p;
        }
#pragma unroll
        for (int off = 32; off; off >>= 1) ss += __shfl_xor(ss, off, 64);
        const float inv = 1.0f / ss;
        for (int k_ = lane; k_ < nk; k_ += 64) sc[r][k_] *= inv;
    }
    __syncthreads();

    // PV: thread = (row-group, dim). 5 rows per thread.
    float acc[5] = {0.f, 0.f, 0.f, 0.f, 0.f};
    const int d = lane, rb = w;
    for (int k0 = 0; k0 < nk; k0 += 64) {
        const int tk = min(64, nk - k0);
        for (int idx = tid; idx < tk * HD; idx += 256) {
            const int kk = idx >> 6, dd = idx & 63;
            kv[kk][dd] = vx[((size_t)b * LFULL + (k0 + kk)) * DDIM + h * HD + dd];
        }
        __syncthreads();
#pragma unroll
        for (int i = 0; i < 5; ++i) {
            const int r = rb + 4 * i;
            float a = acc[i];
            for (int kk = 0; kk < tk; ++kk) a += sc[r][k0 + kk] * kv[kk][d];
            acc[i] = a;
        }
        __syncthreads();
    }
#pragma unroll
    for (int i = 0; i < 5; ++i) {
        const int r = rb + 4 * i;
        out[((size_t)b * NROWS + (s0 * KPS + r)) * DDIM + h * HD + d] = acc[i];
    }
}

// ---------------------------------------------------------------------------
// LayerNorm in place over rows of (32000 x 512); one wave per row.
// ---------------------------------------------------------------------------
__global__ __launch_bounds__(256) void ln_kernel(
    float* __restrict__ f, const float* __restrict__ g, const float* __restrict__ bt)
{
    const int row = blockIdx.x * 4 + (threadIdx.x >> 6);
    const int lane = threadIdx.x & 63;
    float* fr = f + (size_t)row * DDIM;
    float xv[8];
    float s = 0.f;
#pragma unroll
    for (int i = 0; i < 8; ++i) { xv[i] = fr[lane + i * 64]; s += xv[i]; }
#pragma unroll
    for (int off = 32; off; off >>= 1) s += __shfl_xor(s, off, 64);
    const float mu = s * (1.0f / DDIM);
    float var = 0.f;
#pragma unroll
    for (int i = 0; i < 8; ++i) { const float d0 = xv[i] - mu; var += d0 * d0; }
#pragma unroll
    for (int off = 32; off; off >>= 1) var += __shfl_xor(var, off, 64);
    const float rs = rsqrtf(var * (1.0f / DDIM) + 1e-5f);
#pragma unroll
    for (int i = 0; i < 8; ++i) {
        const int d0 = lane + i * 64;
        fr[d0] = (xv[i] - mu) * rs * g[d0] + bt[d0];
    }
}

// ---------------------------------------------------------------------------
// Final head: out[m] = b2 + sum_d h[m,d] * W2[d]; one wave per row.
// ---------------------------------------------------------------------------
__global__ __launch_bounds__(256) void w2_kernel(
    const float* __restrict__ h, const float* __restrict__ W2,
    const float* __restrict__ b2, float* __restrict__ out)
{
    const int row = blockIdx.x * 4 + (threadIdx.x >> 6);
    const int lane = threadIdx.x & 63;
    float s = 0.f;
#pragma unroll
    for (int i = 0; i < 8; ++i) {
        const int d = lane + i * 64;
        s += h[(size_t)row * DDIM + d] * W2[d];
    }
#pragma unroll
    for (int off = 32; off; off >>= 1) s += __shfl_xor(s, off, 64);
    if (lane == 0) out[row] = s + b2[0];
}

// ---------------------------------------------------------------------------
extern "C" void kernel_launch(void* const* d_in, const int* in_sizes, int n_in,
                              void* d_out, int out_size, void* d_ws, size_t ws_size,
                              hipStream_t stream)
{
    const float* item = (const float*)d_in[0];
    const float* user = (const float*)d_in[1];
    const int*   resp = (const int*)d_in[2];
    const float* Wq = (const float*)d_in[3];  const float* bq = (const float*)d_in[4];
    const float* Wk = (const float*)d_in[5];  const float* bk = (const float*)d_in[6];
    const float* Wv = (const float*)d_in[7];  const float* bv = (const float*)d_in[8];
    const float* Wo = (const float*)d_in[9];  const float* bo = (const float*)d_in[10];
    const float* lng = (const float*)d_in[11]; const float* lnb = (const float*)d_in[12];
    const float* W1 = (const float*)d_in[13]; const float* b1 = (const float*)d_in[14];
    const float* W2 = (const float*)d_in[15]; const float* b2 = (const float*)d_in[16];
    float* out = (float*)d_out;
    float* ws  = (float*)d_ws;

    const size_t BLD = (size_t)BATCH * LFULL * DDIM;   // 16,416,768 floats
    const size_t BND = (size_t)BATCH * NROWS * DDIM;   // 16,384,000 floats
    float* qb  = ws;
    float* kb  = qb + BLD;
    float* vb  = kb + BLD;
    float* ao  = vb + BLD;               // attention output / later h
    float* ubq = ao + BND;
    float* ubk = ubq + (size_t)BATCH * DDIM;
    float* ubv = ubk + (size_t)BATCH * DDIM;
    // total ws use: 3*BLD + BND + 3*B*D floats ~= 263 MB

    user_bias_kernel<<<dim3(BATCH), dim3(256), 0, stream>>>(
        user, Wq, bq, Wk, bk, Wv, bv, ubq, ubk, ubv, qb, kb, vb);

    dim3 gg(MTOT / 64, DDIM / 64);   // (500, 8)
    gemm_kernel<0><<<gg, 256, 0, stream>>>(item, Wq, ubq, qb, EDIM);
    gemm_kernel<0><<<gg, 256, 0, stream>>>(item, Wk, ubk, kb, EDIM);
    gemm_kernel<0><<<gg, 256, 0, stream>>>(item, Wv, ubv, vb, EDIM);

    attn_kernel<<<dim3(SLATES, HEADS, BATCH), dim3(256), 0, stream>>>(
        qb, kb, vb, resp, ao);

    // f2 = ao @ Wo^T + bo  -> reuse qb
    gemm_kernel<1><<<gg, 256, 0, stream>>>(ao, Wo, bo, qb, DDIM);
    ln_kernel<<<dim3(MTOT / 4), dim3(256), 0, stream>>>(qb, lng, lnb);
    // h = gelu(f2 @ W1^T + b1) -> reuse ao
    gemm_kernel<2><<<gg, 256, 0, stream>>>(qb, W1, b1, ao, DDIM);
    w2_kernel<<<dim3(MTOT / 4), dim3(256), 0, stream>>>(ao, W2, b2, out);
}

// Round 2
// 662.838 us; speedup vs baseline: 3.3180x; 3.3180x over previous
//
#include <hip/hip_runtime.h>
#include <math.h>

#define BATCH 64
#define SLATES 25
#define KPS 20
#define EDIM 256
#define DDIM 512
#define HEADS 8
#define HD 64
#define LFULL 501
#define NROWS 500
#define MTOT (BATCH*NROWS)   // 32000

typedef __attribute__((ext_vector_type(8))) short short8;
typedef __attribute__((ext_vector_type(4))) float f32x4;

__device__ __forceinline__ unsigned short f2bf(float x) {
    unsigned int u = __builtin_bit_cast(unsigned int, x);
    u = (u + 0x7FFFu + ((u >> 16) & 1u)) >> 16;
    return (unsigned short)u;
}
__device__ __forceinline__ float bf2f(unsigned short s) {
    unsigned int u = ((unsigned int)s) << 16;
    return __builtin_bit_cast(float, u);
}
__device__ __forceinline__ float gelu_exact(float x) {
    return 0.5f * x * (1.0f + erff(x * 0.70710678118654752440f));
}

// ---------------------------------------------------------------------------
// fp32 -> bf16 elementwise convert (n multiple of 4)
// ---------------------------------------------------------------------------
__global__ __launch_bounds__(256) void cvt_kernel(
    const float* __restrict__ src, unsigned short* __restrict__ dst, int n4)
{
    const int i = blockIdx.x * 256 + threadIdx.x;
    if (i >= n4) return;
    float4 v = ((const float4*)src)[i];
    ushort4 o;
    o.x = f2bf(v.x); o.y = f2bf(v.y); o.z = f2bf(v.z); o.w = f2bf(v.w);
    ((ushort4*)dst)[i] = o;
}

// ---------------------------------------------------------------------------
// Per-batch user-projection bias tables (fp32) + row0 of q/k/v (bf16 = bias).
// grid (BATCH, 3): y selects {q,k,v}.
// ---------------------------------------------------------------------------
__global__ __launch_bounds__(256) void user_bias_kernel(
    const float* __restrict__ user,
    const float* __restrict__ Wq, const float* __restrict__ bq,
    const float* __restrict__ Wk, const float* __restrict__ bk,
    const float* __restrict__ Wv, const float* __restrict__ bv,
    float* __restrict__ ubq, float* __restrict__ ubk, float* __restrict__ ubv,
    unsigned short* __restrict__ qb, unsigned short* __restrict__ kb,
    unsigned short* __restrict__ vb)
{
    const int b = blockIdx.x;
    const int y = blockIdx.y;
    const int tid = threadIdx.x;
    const float* W  = (y == 0) ? Wq : (y == 1) ? Wk : Wv;
    const float* bi = (y == 0) ? bq : (y == 1) ? bk : bv;
    float* ub = (y == 0) ? ubq : (y == 1) ? ubk : ubv;
    unsigned short* r0 = (y == 0) ? qb : (y == 1) ? kb : vb;

    __shared__ float us[EDIM];
    if (tid < EDIM) us[tid] = user[b * EDIM + tid];
    __syncthreads();
    for (int o = tid; o < DDIM; o += 256) {
        float s = bi[o];
        const float* wr = &W[(size_t)o * DDIM + EDIM];
#pragma unroll 4
        for (int e = 0; e < EDIM; ++e) s += us[e] * wr[e];
        ub[b * DDIM + o] = s;
        r0[(size_t)b * LFULL * DDIM + o] = f2bf(bi[o]);
    }
}

// ---------------------------------------------------------------------------
// bf16 MFMA GEMM: C = A(M x Kdim, bf16, lda) @ W(512 x Kdim window, bf16,
// row stride 512)^T.  Tile 128x128, BK=32, 256 thr = 4 waves (2x2), each wave
// 64x64 via 4x4 16x16 fragments.
// MODE 0: +ub[b][n] per-batch bias, scatter bf16 to (b, m%500+1, n) of
//         (B,501,512); MODE 1: +bias[n], fp32 out; MODE 2: gelu, bf16 out.
// ---------------------------------------------------------------------------
template <int MODE>
__global__ __launch_bounds__(256) void gemm_bf16(
    const unsigned short* __restrict__ A, int lda, int Kdim,
    const unsigned short* __restrict__ W,
    const float* __restrict__ bias, void* __restrict__ outp)
{
    const int tid = threadIdx.x;
    const int n0 = blockIdx.x * 128;
    const int m0 = blockIdx.y * 128;
    const int lane = tid & 63, wid = tid >> 6;
    const int wm = (wid & 1) * 64, wn = (wid >> 1) * 64;

    __shared__ unsigned short As[128][40];
    __shared__ unsigned short Ws[128][40];

    f32x4 acc[4][4];
#pragma unroll
    for (int i = 0; i < 4; ++i)
#pragma unroll
        for (int j = 0; j < 4; ++j) acc[i][j] = (f32x4){0.f, 0.f, 0.f, 0.f};

    const int srow = tid >> 1, sseg = (tid & 1) * 16;
    const unsigned short* gA = &A[(size_t)(m0 + srow) * lda + sseg];
    const unsigned short* gW = &W[(size_t)(n0 + srow) * DDIM + sseg];

    const int frow = lane & 15, fk = (lane >> 4) * 8;

    for (int k0 = 0; k0 < Kdim; k0 += 32) {
        uint4 a0 = *(const uint4*)(gA + k0);
        uint4 a1 = *(const uint4*)(gA + k0 + 8);
        uint4 w0 = *(const uint4*)(gW + k0);
        uint4 w1 = *(const uint4*)(gW + k0 + 8);
        __syncthreads();
        *(uint4*)&As[srow][sseg]     = a0;
        *(uint4*)&As[srow][sseg + 8] = a1;
        *(uint4*)&Ws[srow][sseg]     = w0;
        *(uint4*)&Ws[srow][sseg + 8] = w1;
        __syncthreads();
        short8 af[4], wf[4];
#pragma unroll
        for (int mi = 0; mi < 4; ++mi)
            af[mi] = *(const short8*)&As[wm + mi * 16 + frow][fk];
#pragma unroll
        for (int ni = 0; ni < 4; ++ni)
            wf[ni] = *(const short8*)&Ws[wn + ni * 16 + frow][fk];
#pragma unroll
        for (int mi = 0; mi < 4; ++mi)
#pragma unroll
            for (int ni = 0; ni < 4; ++ni)
                acc[mi][ni] = __builtin_amdgcn_mfma_f32_16x16x32_bf16(
                    af[mi], wf[ni], acc[mi][ni], 0, 0, 0);
    }

#pragma unroll
    for (int mi = 0; mi < 4; ++mi) {
#pragma unroll
        for (int ni = 0; ni < 4; ++ni) {
            const int n = n0 + wn + ni * 16 + (lane & 15);
#pragma unroll
            for (int r = 0; r < 4; ++r) {
                const int m = m0 + wm + mi * 16 + (lane >> 4) * 4 + r;
                float v = acc[mi][ni][r];
                if (MODE == 0) {
                    const int b = m / NROWS;
                    const int l = m - b * NROWS + 1;
                    v += bias[(size_t)b * DDIM + n];
                    ((unsigned short*)outp)[((size_t)b * LFULL + l) * DDIM + n] = f2bf(v);
                } else if (MODE == 1) {
                    ((float*)outp)[(size_t)m * DDIM + n] = v + bias[n];
                } else {
                    ((unsigned short*)outp)[(size_t)m * DDIM + n] =
                        f2bf(gelu_exact(v + bias[n]));
                }
            }
        }
    }
}

// ---------------------------------------------------------------------------
// MFMA attention. Block per (slate, head, batch). Q (20x64) in register
// fragments; K staged in LDS; scores -> LDS; wave softmax; V staged
// transposed; PV via MFMA. Output bf16 compact (B,500,512).
// ---------------------------------------------------------------------------
__global__ __launch_bounds__(256) void attn_mfma(
    const unsigned short* __restrict__ qx, const unsigned short* __restrict__ kx,
    const unsigned short* __restrict__ vx, const int* __restrict__ resp,
    unsigned short* __restrict__ outb)
{
    const int s0 = blockIdx.x, h = blockIdx.y, b = blockIdx.z;
    const int tid = threadIdx.x, lane = tid & 63, w = tid >> 6;
    const int nk = s0 * KPS + 1;
    const int nkt = (nk + 31) >> 5;
    const int NK = nkt << 5;          // <= 512

    __shared__ float sc[KPS][516];
    __shared__ union {
        unsigned short kt[32][72];
        unsigned short vt[64][40];
    } u;

    const int frow = lane & 15, fk = (lane >> 4) * 8;

    // Q fragments (same for all waves): rows mi*16+frow, k = ks*32+fk
    short8 qf[2][2];
#pragma unroll
    for (int mi = 0; mi < 2; ++mi) {
        const int qrow = mi * 16 + frow;
#pragma unroll
        for (int ks = 0; ks < 2; ++ks) {
            short8 v = {};
            if (qrow < KPS)
                v = *(const short8*)&qx[(((size_t)b * LFULL) + s0 * KPS + 1 + qrow) * DDIM
                                        + h * HD + ks * 32 + fk];
            qf[mi][ks] = v;
        }
    }

    // ---- QK^T ----
    const int skey = tid >> 3, sseg = (tid & 7) * 8;
    for (int t0 = 0; t0 < NK; t0 += 32) {
        uint4 kraw = {0u, 0u, 0u, 0u};
        const int gk = t0 + skey;
        if (gk < nk)
            kraw = *(const uint4*)&kx[(((size_t)b * LFULL) + gk) * DDIM + h * HD + sseg];
        __syncthreads();
        *(uint4*)&u.kt[skey][sseg] = kraw;
        __syncthreads();

        f32x4 s2[2][2];
#pragma unroll
        for (int mi = 0; mi < 2; ++mi)
#pragma unroll
            for (int ni = 0; ni < 2; ++ni) s2[mi][ni] = (f32x4){0.f, 0.f, 0.f, 0.f};
        short8 kf[2][2];
#pragma unroll
        for (int ni = 0; ni < 2; ++ni)
#pragma unroll
            for (int ks = 0; ks < 2; ++ks)
                kf[ni][ks] = *(const short8*)&u.kt[ni * 16 + frow][ks * 32 + fk];
#pragma unroll
        for (int mi = 0; mi < 2; ++mi)
#pragma unroll
            for (int ni = 0; ni < 2; ++ni) {
                s2[mi][ni] = __builtin_amdgcn_mfma_f32_16x16x32_bf16(
                    qf[mi][0], kf[ni][0], s2[mi][ni], 0, 0, 0);
                s2[mi][ni] = __builtin_amdgcn_mfma_f32_16x16x32_bf16(
                    qf[mi][1], kf[ni][1], s2[mi][ni], 0, 0, 0);
            }
#pragma unroll
        for (int ni = 0; ni < 2; ++ni) {
            const int key = t0 + ni * 16 + (lane & 15);
            const bool allow = (key == 0) || (key < nk && resp[(size_t)b * NROWS + key - 1] > 0);
#pragma unroll
            for (int mi = 0; mi < 2; ++mi)
#pragma unroll
                for (int r = 0; r < 4; ++r) {
                    const int row = mi * 16 + (lane >> 4) * 4 + r;
                    if (row < KPS)
                        sc[row][key] = allow ? s2[mi][ni][r] * 0.125f : -1e30f;
                }
        }
    }
    __syncthreads();

    // ---- softmax (wave per row) ----
    for (int r = w; r < KPS; r += 4) {
        float mx = -1e30f;
        for (int k_ = lane; k_ < nk; k_ += 64) mx = fmaxf(mx, sc[r][k_]);
#pragma unroll
        for (int off = 32; off; off >>= 1) mx = fmaxf(mx, __shfl_xor(mx, off, 64));
        float ss = 0.f;
        for (int k_ = lane; k_ < nk; k_ += 64) {
            const float p = __expf(sc[r][k_] - mx);
            sc[r][k_] = p;
            ss += p;
        }
#pragma unroll
        for (int off = 32; off; off >>= 1) ss += __shfl_xor(ss, off, 64);
        const float inv = 1.0f / ss;
        for (int k_ = lane; k_ < nk; k_ += 64) sc[r][k_] *= inv;
        for (int k_ = nk + lane; k_ < NK; k_ += 64) sc[r][k_] = 0.f;
    }
    __syncthreads();

    // ---- PV ----
    f32x4 po[2][4];
#pragma unroll
    for (int mi = 0; mi < 2; ++mi)
#pragma unroll
        for (int nd = 0; nd < 4; ++nd) po[mi][nd] = (f32x4){0.f, 0.f, 0.f, 0.f};

    const int vkey = tid & 31, vseg = (tid >> 5) * 8;
    for (int t0 = 0; t0 < NK; t0 += 32) {
        uint4 vraw = {0u, 0u, 0u, 0u};
        if (t0 + vkey < nk)
            vraw = *(const uint4*)&vx[(((size_t)b * LFULL) + t0 + vkey) * DDIM + h * HD + vseg];
        __syncthreads();
        {
            const unsigned short* pr = (const unsigned short*)&vraw;
#pragma unroll
            for (int j = 0; j < 8; ++j) u.vt[vseg + j][vkey] = pr[j];
        }
        __syncthreads();

        short8 pf[2];
#pragma unroll
        for (int mi = 0; mi < 2; ++mi) {
            short8 t = {};
            const int row = mi * 16 + frow;
            if (row < KPS) {
                const float* sp = &sc[row][t0 + fk];
#pragma unroll
                for (int j = 0; j < 8; ++j) t[j] = (short)f2bf(sp[j]);
            }
            pf[mi] = t;
        }
        short8 vf[4];
#pragma unroll
        for (int nd = 0; nd < 4; ++nd)
            vf[nd] = *(const short8*)&u.vt[nd * 16 + frow][fk];
#pragma unroll
        for (int mi = 0; mi < 2; ++mi)
#pragma unroll
            for (int nd = 0; nd < 4; ++nd)
                po[mi][nd] = __builtin_amdgcn_mfma_f32_16x16x32_bf16(
                    pf[mi], vf[nd], po[mi][nd], 0, 0, 0);
    }

#pragma unroll
    for (int mi = 0; mi < 2; ++mi)
#pragma unroll
        for (int nd = 0; nd < 4; ++nd)
#pragma unroll
            for (int r = 0; r < 4; ++r) {
                const int row = mi * 16 + (lane >> 4) * 4 + r;
                if (row < KPS)
                    outb[((size_t)b * NROWS + s0 * KPS + row) * DDIM
                         + h * HD + nd * 16 + (lane & 15)] = f2bf(po[mi][nd][r]);
            }
}

// ---------------------------------------------------------------------------
// LayerNorm: read fp32 f, write bf16 (for W1 GEMM). One wave per row.
// ---------------------------------------------------------------------------
__global__ __launch_bounds__(256) void ln_kernel(
    const float* __restrict__ f, const float* __restrict__ g,
    const float* __restrict__ bt, unsigned short* __restrict__ o)
{
    const int row = blockIdx.x * 4 + (threadIdx.x >> 6);
    const int lane = threadIdx.x & 63;
    const float* fr = f + (size_t)row * DDIM;
    float xv[8];
    float s = 0.f;
#pragma unroll
    for (int i = 0; i < 8; ++i) { xv[i] = fr[lane + i * 64]; s += xv[i]; }
#pragma unroll
    for (int off = 32; off; off >>= 1) s += __shfl_xor(s, off, 64);
    const float mu = s * (1.0f / DDIM);
    float var = 0.f;
#pragma unroll
    for (int i = 0; i < 8; ++i) { const float d0 = xv[i] - mu; var += d0 * d0; }
#pragma unroll
    for (int off = 32; off; off >>= 1) var += __shfl_xor(var, off, 64);
    const float rs = rsqrtf(var * (1.0f / DDIM) + 1e-5f);
#pragma unroll
    for (int i = 0; i < 8; ++i) {
        const int d0 = lane + i * 64;
        o[(size_t)row * DDIM + d0] = f2bf((xv[i] - mu) * rs * g[d0] + bt[d0]);
    }
}

// ---------------------------------------------------------------------------
// Final head: out[m] = b2 + sum_d h[m,d]*W2[d]; h is bf16.
// ---------------------------------------------------------------------------
__global__ __launch_bounds__(256) void w2_kernel(
    const unsigned short* __restrict__ h, const float* __restrict__ W2,
    const float* __restrict__ b2, float* __restrict__ out)
{
    const int row = blockIdx.x * 4 + (threadIdx.x >> 6);
    const int lane = threadIdx.x & 63;
    float s = 0.f;
#pragma unroll
    for (int i = 0; i < 8; ++i) {
        const int d = lane + i * 64;
        s += bf2f(h[(size_t)row * DDIM + d]) * W2[d];
    }
#pragma unroll
    for (int off = 32; off; off >>= 1) s += __shfl_xor(s, off, 64);
    if (lane == 0) out[row] = s + b2[0];
}

// ---------------------------------------------------------------------------
extern "C" void kernel_launch(void* const* d_in, const int* in_sizes, int n_in,
                              void* d_out, int out_size, void* d_ws, size_t ws_size,
                              hipStream_t stream)
{
    const float* item = (const float*)d_in[0];
    const float* user = (const float*)d_in[1];
    const int*   resp = (const int*)d_in[2];
    const float* Wq = (const float*)d_in[3];  const float* bq = (const float*)d_in[4];
    const float* Wk = (const float*)d_in[5];  const float* bk = (const float*)d_in[6];
    const float* Wv = (const float*)d_in[7];  const float* bv = (const float*)d_in[8];
    const float* Wo = (const float*)d_in[9];  const float* bo = (const float*)d_in[10];
    const float* lng = (const float*)d_in[11]; const float* lnb = (const float*)d_in[12];
    const float* W1 = (const float*)d_in[13]; const float* b1 = (const float*)d_in[14];
    const float* W2 = (const float*)d_in[15]; const float* b2 = (const float*)d_in[16];
    float* out = (float*)d_out;

    char* p = (char*)d_ws;
    auto alloc = [&](size_t bytes) { char* r = p; p += (bytes + 255) & ~(size_t)255; return r; };
    const size_t NITEM = (size_t)BATCH * NROWS * EDIM;        // 8,192,000
    const size_t NW    = (size_t)DDIM * DDIM;                 // 262,144
    const size_t NQKV  = (size_t)BATCH * LFULL * DDIM;        // 16,416,768
    const size_t NMD   = (size_t)MTOT * DDIM;                 // 16,384,000

    unsigned short* itemb = (unsigned short*)alloc(NITEM * 2);
    unsigned short* Wqb = (unsigned short*)alloc(NW * 2);
    unsigned short* Wkb = (unsigned short*)alloc(NW * 2);
    unsigned short* Wvb = (unsigned short*)alloc(NW * 2);
    unsigned short* Wob = (unsigned short*)alloc(NW * 2);
    unsigned short* W1b = (unsigned short*)alloc(NW * 2);
    unsigned short* qb  = (unsigned short*)alloc(NQKV * 2);
    unsigned short* kb  = (unsigned short*)alloc(NQKV * 2);
    unsigned short* vb  = (unsigned short*)alloc(NQKV * 2);
    unsigned short* aob = (unsigned short*)alloc(NMD * 2);
    unsigned short* hb  = (unsigned short*)alloc(NMD * 2);
    float* fbuf = (float*)alloc(NMD * 4);
    float* ubq  = (float*)alloc((size_t)BATCH * DDIM * 4);
    float* ubk  = (float*)alloc((size_t)BATCH * DDIM * 4);
    float* ubv  = (float*)alloc((size_t)BATCH * DDIM * 4);

    // converts
    cvt_kernel<<<dim3((NITEM / 4 + 255) / 256), 256, 0, stream>>>(item, itemb, NITEM / 4);
    cvt_kernel<<<dim3(NW / 4 / 256), 256, 0, stream>>>(Wq, Wqb, NW / 4);
    cvt_kernel<<<dim3(NW / 4 / 256), 256, 0, stream>>>(Wk, Wkb, NW / 4);
    cvt_kernel<<<dim3(NW / 4 / 256), 256, 0, stream>>>(Wv, Wvb, NW / 4);
    cvt_kernel<<<dim3(NW / 4 / 256), 256, 0, stream>>>(Wo, Wob, NW / 4);
    cvt_kernel<<<dim3(NW / 4 / 256), 256, 0, stream>>>(W1, W1b, NW / 4);

    user_bias_kernel<<<dim3(BATCH, 3), 256, 0, stream>>>(
        user, Wq, bq, Wk, bk, Wv, bv, ubq, ubk, ubv, qb, kb, vb);

    // QKV projections (A = itemb, Kdim=256; weights use cols 0..255 only)
    dim3 gg(DDIM / 128, MTOT / 128);   // (4, 250), n fastest
    gemm_bf16<0><<<gg, 256, 0, stream>>>(itemb, EDIM, EDIM, Wqb, ubq, qb);
    gemm_bf16<0><<<gg, 256, 0, stream>>>(itemb, EDIM, EDIM, Wkb, ubk, kb);
    gemm_bf16<0><<<gg, 256, 0, stream>>>(itemb, EDIM, EDIM, Wvb, ubv, vb);

    attn_mfma<<<dim3(SLATES, HEADS, BATCH), 256, 0, stream>>>(qb, kb, vb, resp, aob);

    // f = ao @ Wo^T + bo (fp32)
    gemm_bf16<1><<<gg, 256, 0, stream>>>(aob, DDIM, DDIM, Wob, bo, fbuf);
    // LN -> bf16 (reuse aob as destination)
    ln_kernel<<<dim3(MTOT / 4), 256, 0, stream>>>(fbuf, lng, lnb, aob);
    // h = gelu(ln @ W1^T + b1) -> bf16
    gemm_bf16<2><<<gg, 256, 0, stream>>>(aob, DDIM, DDIM, W1b, b1, hb);
    w2_kernel<<<dim3(MTOT / 4), 256, 0, stream>>>(hb, W2, b2, out);
}

// Round 3
// 449.123 us; speedup vs baseline: 4.8968x; 1.4758x over previous
//
#include <hip/hip_runtime.h>
#include <math.h>

#define BATCH 64
#define SLATES 25
#define KPS 20
#define EDIM 256
#define DDIM 512
#define HEADS 8
#define HD 64
#define LFULL 501
#define NROWS 500
#define MTOT (BATCH*NROWS)   // 32000

typedef __attribute__((ext_vector_type(8))) short short8;
typedef __attribute__((ext_vector_type(4))) float f32x4;

__device__ __forceinline__ unsigned short f2bf(float x) {
    unsigned int u = __builtin_bit_cast(unsigned int, x);
    u = (u + 0x7FFFu + ((u >> 16) & 1u)) >> 16;
    return (unsigned short)u;
}
__device__ __forceinline__ float bf2f(unsigned short s) {
    unsigned int u = ((unsigned int)s) << 16;
    return __builtin_bit_cast(float, u);
}
__device__ __forceinline__ float gelu_exact(float x) {
    return 0.5f * x * (1.0f + erff(x * 0.70710678118654752440f));
}

// ---------------------------------------------------------------------------
// fp32 -> bf16 converts
// ---------------------------------------------------------------------------
__global__ __launch_bounds__(256) void cvt_kernel(
    const float* __restrict__ src, unsigned short* __restrict__ dst, int n4)
{
    const int i = blockIdx.x * 256 + threadIdx.x;
    if (i >= n4) return;
    float4 v = ((const float4*)src)[i];
    ushort4 o;
    o.x = f2bf(v.x); o.y = f2bf(v.y); o.z = f2bf(v.z); o.w = f2bf(v.w);
    ((ushort4*)dst)[i] = o;
}

struct Cvt5 { const float* s[5]; unsigned short* d[5]; };
__global__ __launch_bounds__(256) void cvt5_kernel(Cvt5 a, int n4)
{
    const int i = blockIdx.x * 256 + threadIdx.x;
    if (i >= n4) return;
    const int y = blockIdx.y;
    float4 v = ((const float4*)a.s[y])[i];
    ushort4 o;
    o.x = f2bf(v.x); o.y = f2bf(v.y); o.z = f2bf(v.z); o.w = f2bf(v.w);
    ((ushort4*)a.d[y])[i] = o;
}

// ---------------------------------------------------------------------------
// Per-batch user-projection bias tables (fp32) + row0 of q/k/v (head-major).
// ---------------------------------------------------------------------------
__global__ __launch_bounds__(256) void user_bias_kernel(
    const float* __restrict__ user,
    const float* __restrict__ Wq, const float* __restrict__ bq,
    const float* __restrict__ Wk, const float* __restrict__ bk,
    const float* __restrict__ Wv, const float* __restrict__ bv,
    float* __restrict__ ubq, float* __restrict__ ubk, float* __restrict__ ubv,
    unsigned short* __restrict__ qb, unsigned short* __restrict__ kb,
    unsigned short* __restrict__ vb)
{
    const int b = blockIdx.x;
    const int y = blockIdx.y;
    const int tid = threadIdx.x;
    const float* W  = (y == 0) ? Wq : (y == 1) ? Wk : Wv;
    const float* bi = (y == 0) ? bq : (y == 1) ? bk : bv;
    float* ub = (y == 0) ? ubq : (y == 1) ? ubk : ubv;
    unsigned short* r0 = (y == 0) ? qb : (y == 1) ? kb : vb;

    __shared__ float us[EDIM];
    if (tid < EDIM) us[tid] = user[b * EDIM + tid];
    __syncthreads();
    for (int o = tid; o < DDIM; o += 256) {
        float s = bi[o];
        const float* wr = &W[(size_t)o * DDIM + EDIM];
#pragma unroll 4
        for (int e = 0; e < EDIM; ++e) s += us[e] * wr[e];
        ub[b * DDIM + o] = s;
        // head-major row 0: ((b*H + o/64)*LFULL + 0)*64 + (o&63)
        r0[(((size_t)b * HEADS + (o >> 6)) * LFULL) * HD + (o & 63)] = f2bf(bi[o]);
    }
}

// ---------------------------------------------------------------------------
// Fused QKV GEMM: C = item(M x 256) @ W(512 x [0:256])^T + ub[b]; output
// head-major bf16 (B, H, 501, 64) at row l = m%500 + 1. blockIdx.z picks q/k/v.
// Tile 128x128, BK=32, 4 waves (2x2), 4x4 16x16x32 frags per wave.
// ---------------------------------------------------------------------------
__global__ __launch_bounds__(256) void gemm_qkv(
    const unsigned short* __restrict__ A,
    const unsigned short* __restrict__ Wq, const unsigned short* __restrict__ Wk,
    const unsigned short* __restrict__ Wv,
    const float* __restrict__ uq, const float* __restrict__ uk,
    const float* __restrict__ uv,
    unsigned short* __restrict__ oq, unsigned short* __restrict__ ok,
    unsigned short* __restrict__ ov)
{
    const int z = blockIdx.z;
    const unsigned short* W = (z == 0) ? Wq : (z == 1) ? Wk : Wv;
    const float* ub = (z == 0) ? uq : (z == 1) ? uk : uv;
    unsigned short* outp = (z == 0) ? oq : (z == 1) ? ok : ov;

    const int tid = threadIdx.x;
    const int n0 = blockIdx.x * 128;
    const int m0 = blockIdx.y * 128;
    const int lane = tid & 63, wid = tid >> 6;
    const int wm = (wid & 1) * 64, wn = (wid >> 1) * 64;

    __shared__ unsigned short As[128][40];
    __shared__ unsigned short Ws[128][40];

    f32x4 acc[4][4];
#pragma unroll
    for (int i = 0; i < 4; ++i)
#pragma unroll
        for (int j = 0; j < 4; ++j) acc[i][j] = (f32x4){0.f, 0.f, 0.f, 0.f};

    const int srow = tid >> 1, sseg = (tid & 1) * 16;
    const unsigned short* gA = &A[(size_t)(m0 + srow) * EDIM + sseg];
    const unsigned short* gW = &W[(size_t)(n0 + srow) * DDIM + sseg];
    const int frow = lane & 15, fk = (lane >> 4) * 8;

    for (int k0 = 0; k0 < EDIM; k0 += 32) {
        uint4 a0 = *(const uint4*)(gA + k0);
        uint4 a1 = *(const uint4*)(gA + k0 + 8);
        uint4 w0 = *(const uint4*)(gW + k0);
        uint4 w1 = *(const uint4*)(gW + k0 + 8);
        __syncthreads();
        *(uint4*)&As[srow][sseg]     = a0;
        *(uint4*)&As[srow][sseg + 8] = a1;
        *(uint4*)&Ws[srow][sseg]     = w0;
        *(uint4*)&Ws[srow][sseg + 8] = w1;
        __syncthreads();
        short8 af[4], wf[4];
#pragma unroll
        for (int mi = 0; mi < 4; ++mi)
            af[mi] = *(const short8*)&As[wm + mi * 16 + frow][fk];
#pragma unroll
        for (int ni = 0; ni < 4; ++ni)
            wf[ni] = *(const short8*)&Ws[wn + ni * 16 + frow][fk];
#pragma unroll
        for (int mi = 0; mi < 4; ++mi)
#pragma unroll
            for (int ni = 0; ni < 4; ++ni)
                acc[mi][ni] = __builtin_amdgcn_mfma_f32_16x16x32_bf16(
                    af[mi], wf[ni], acc[mi][ni], 0, 0, 0);
    }

#pragma unroll
    for (int mi = 0; mi < 4; ++mi) {
#pragma unroll
        for (int ni = 0; ni < 4; ++ni) {
            const int n = n0 + wn + ni * 16 + (lane & 15);
            const int hh = n >> 6, dd = n & 63;
#pragma unroll
            for (int r = 0; r < 4; ++r) {
                const int m = m0 + wm + mi * 16 + (lane >> 4) * 4 + r;
                const int b = m / NROWS;
                const int l = m - b * NROWS + 1;
                const float v = acc[mi][ni][r] + ub[(size_t)b * DDIM + n];
                outp[(((size_t)b * HEADS + hh) * LFULL + l) * HD + dd] = f2bf(v);
            }
        }
    }
}

// ---------------------------------------------------------------------------
// Generic bf16 GEMM for Wo / W1 stages (A row-major 512, W 512x512).
// MODE 1: +bias, fp32 out. MODE 2: +bias + gelu, bf16 out.
// ---------------------------------------------------------------------------
template <int MODE>
__global__ __launch_bounds__(256) void gemm_bf16(
    const unsigned short* __restrict__ A,
    const unsigned short* __restrict__ W,
    const float* __restrict__ bias, void* __restrict__ outp)
{
    const int tid = threadIdx.x;
    const int n0 = blockIdx.x * 128;
    const int m0 = blockIdx.y * 128;
    const int lane = tid & 63, wid = tid >> 6;
    const int wm = (wid & 1) * 64, wn = (wid >> 1) * 64;

    __shared__ unsigned short As[128][40];
    __shared__ unsigned short Ws[128][40];

    f32x4 acc[4][4];
#pragma unroll
    for (int i = 0; i < 4; ++i)
#pragma unroll
        for (int j = 0; j < 4; ++j) acc[i][j] = (f32x4){0.f, 0.f, 0.f, 0.f};

    const int srow = tid >> 1, sseg = (tid & 1) * 16;
    const unsigned short* gA = &A[(size_t)(m0 + srow) * DDIM + sseg];
    const unsigned short* gW = &W[(size_t)(n0 + srow) * DDIM + sseg];
    const int frow = lane & 15, fk = (lane >> 4) * 8;

    for (int k0 = 0; k0 < DDIM; k0 += 32) {
        uint4 a0 = *(const uint4*)(gA + k0);
        uint4 a1 = *(const uint4*)(gA + k0 + 8);
        uint4 w0 = *(const uint4*)(gW + k0);
        uint4 w1 = *(const uint4*)(gW + k0 + 8);
        __syncthreads();
        *(uint4*)&As[srow][sseg]     = a0;
        *(uint4*)&As[srow][sseg + 8] = a1;
        *(uint4*)&Ws[srow][sseg]     = w0;
        *(uint4*)&Ws[srow][sseg + 8] = w1;
        __syncthreads();
        short8 af[4], wf[4];
#pragma unroll
        for (int mi = 0; mi < 4; ++mi)
            af[mi] = *(const short8*)&As[wm + mi * 16 + frow][fk];
#pragma unroll
        for (int ni = 0; ni < 4; ++ni)
            wf[ni] = *(const short8*)&Ws[wn + ni * 16 + frow][fk];
#pragma unroll
        for (int mi = 0; mi < 4; ++mi)
#pragma unroll
            for (int ni = 0; ni < 4; ++ni)
                acc[mi][ni] = __builtin_amdgcn_mfma_f32_16x16x32_bf16(
                    af[mi], wf[ni], acc[mi][ni], 0, 0, 0);
    }

#pragma unroll
    for (int mi = 0; mi < 4; ++mi) {
#pragma unroll
        for (int ni = 0; ni < 4; ++ni) {
            const int n = n0 + wn + ni * 16 + (lane & 15);
#pragma unroll
            for (int r = 0; r < 4; ++r) {
                const int m = m0 + wm + mi * 16 + (lane >> 4) * 4 + r;
                const float v = acc[mi][ni][r] + bias[n];
                if (MODE == 1) {
                    ((float*)outp)[(size_t)m * DDIM + n] = v;
                } else {
                    ((unsigned short*)outp)[(size_t)m * DDIM + n] = f2bf(gelu_exact(v));
                }
            }
        }
    }
}

// ---------------------------------------------------------------------------
// Attention v3. Block = (slate, head, batch), 256 thr / 4 waves.
// QK^T: 64-key supertiles, key-split across waves (wave w -> 16 keys).
// Softmax: wave per row; P converted bf16 IN PLACE into scf rows.
// PV: dim-split across waves (wave w -> dims w*16..w*16+15), no reduction.
// q/k/v are head-major (B,H,501,64) bf16. Output compact (B,500,512) bf16.
// ---------------------------------------------------------------------------
__global__ __launch_bounds__(256) void attn_mfma(
    const unsigned short* __restrict__ qx, const unsigned short* __restrict__ kx,
    const unsigned short* __restrict__ vx, const int* __restrict__ resp,
    unsigned short* __restrict__ outb)
{
    const int s0 = blockIdx.x, h = blockIdx.y, b = blockIdx.z;
    const int tid = threadIdx.x, lane = tid & 63, w = tid >> 6;
    const int nk = s0 * KPS + 1;
    const int NT = (nk + 63) >> 6;     // 64-key tiles
    const int NK = NT << 6;            // <= 512

    __shared__ float scf[KPS][516];    // scores; rows become bf16 P in place
    __shared__ float invb[KPS];
    __shared__ unsigned short stg[64][72];   // K tile / V^T tile

    const int frow = lane & 15, fk = (lane >> 4) * 8;
    const size_t bh = (size_t)b * HEADS + h;
    const unsigned short* kbase = kx + bh * LFULL * HD;
    const unsigned short* vbase = vx + bh * LFULL * HD;

    // Q fragments: rows mi*16+frow (guard <20), k = ks*32+fk
    short8 qf[2][2];
#pragma unroll
    for (int mi = 0; mi < 2; ++mi) {
        const int qrow = mi * 16 + frow;
#pragma unroll
        for (int ks = 0; ks < 2; ++ks) {
            short8 v = {};
            if (qrow < KPS)
                v = *(const short8*)&qx[(bh * LFULL + s0 * KPS + 1 + qrow) * HD
                                        + ks * 32 + fk];
            qf[mi][ks] = v;
        }
    }

    // ---- QK^T ----
    for (int t = 0; t < NT; ++t) {
        const int t0 = t << 6;
        {   // stage 64 K rows: fully coalesced 8 KB
            const int key = tid >> 2, seg = (tid & 3) * 16;
            const int gk = t0 + key;
            uint4 r0 = {0u,0u,0u,0u}, r1 = {0u,0u,0u,0u};
            if (gk < nk) {
                const unsigned short* p = kbase + (size_t)gk * HD + seg;
                r0 = *(const uint4*)p;
                r1 = *(const uint4*)(p + 8);
            }
            __syncthreads();
            *(uint4*)&stg[key][seg]     = r0;
            *(uint4*)&stg[key][seg + 8] = r1;
            __syncthreads();
        }
        // wave's 16-key slice
        short8 kf[2];
#pragma unroll
        for (int ks = 0; ks < 2; ++ks)
            kf[ks] = *(const short8*)&stg[w * 16 + frow][ks * 32 + fk];
        f32x4 s2[2];
#pragma unroll
        for (int mi = 0; mi < 2; ++mi) {
            s2[mi] = (f32x4){0.f, 0.f, 0.f, 0.f};
            s2[mi] = __builtin_amdgcn_mfma_f32_16x16x32_bf16(qf[mi][0], kf[0], s2[mi], 0, 0, 0);
            s2[mi] = __builtin_amdgcn_mfma_f32_16x16x32_bf16(qf[mi][1], kf[1], s2[mi], 0, 0, 0);
        }
        const int key = t0 + w * 16 + frow;
        const bool allow = (key == 0) || (key < nk && resp[(size_t)b * NROWS + key - 1] > 0);
#pragma unroll
        for (int mi = 0; mi < 2; ++mi)
#pragma unroll
            for (int r = 0; r < 4; ++r) {
                const int row = mi * 16 + (lane >> 4) * 4 + r;
                if (row < KPS)
                    scf[row][key] = allow ? s2[mi][r] * 0.125f : -1e30f;
            }
    }
    __syncthreads();

    // ---- softmax (wave per row), write bf16 P in place ----
    for (int r = w; r < KPS; r += 4) {
        float xv[8];
        float mx = -1e30f;
        const int cnt = (NK - lane + 63) >> 6;   // iterations for this lane
#pragma unroll
        for (int i = 0; i < 8; ++i) {
            const int k_ = lane + i * 64;
            if (k_ < NK) { xv[i] = scf[r][k_]; mx = fmaxf(mx, xv[i]); }
        }
#pragma unroll
        for (int off = 32; off; off >>= 1) mx = fmaxf(mx, __shfl_xor(mx, off, 64));
        float ss = 0.f;
        unsigned short* pr = (unsigned short*)&scf[r][0];
#pragma unroll
        for (int i = 0; i < 8; ++i) {
            const int k_ = lane + i * 64;
            if (k_ < NK) {
                const float p = __expf(xv[i] - mx);
                ss += p;
                pr[k_] = f2bf(p);
            }
        }
        (void)cnt;
#pragma unroll
        for (int off = 32; off; off >>= 1) ss += __shfl_xor(ss, off, 64);
        if (lane == 0) invb[r] = 1.0f / ss;
    }
    __syncthreads();

    // ---- PV (dim-split: wave w owns dims w*16..w*16+15) ----
    f32x4 po[2];
    po[0] = (f32x4){0.f, 0.f, 0.f, 0.f};
    po[1] = (f32x4){0.f, 0.f, 0.f, 0.f};
    for (int t = 0; t < NT; ++t) {
        const int t0 = t << 6;
        {   // stage V transposed: vt[dim][key]; wave w loads its 16 dims
            const int key = tid & 63, seg = (tid >> 6) * 16;
            uint4 r0 = {0u,0u,0u,0u}, r1 = {0u,0u,0u,0u};
            if (t0 + key < nk) {
                const unsigned short* p = vbase + (size_t)(t0 + key) * HD + seg;
                r0 = *(const uint4*)p;
                r1 = *(const uint4*)(p + 8);
            }
            __syncthreads();
            const unsigned short* e0 = (const unsigned short*)&r0;
            const unsigned short* e1 = (const unsigned short*)&r1;
#pragma unroll
            for (int j = 0; j < 8; ++j) stg[seg + j][key] = e0[j];
#pragma unroll
            for (int j = 0; j < 8; ++j) stg[seg + 8 + j][key] = e1[j];
            __syncthreads();
        }
#pragma unroll
        for (int ks = 0; ks < 2; ++ks) {
            const short8 vf = *(const short8*)&stg[w * 16 + frow][ks * 32 + fk];
#pragma unroll
            for (int mi = 0; mi < 2; ++mi) {
                short8 pf = {};
                const int prow = mi * 16 + frow;
                if (prow < KPS)
                    pf = *(const short8*)((const unsigned short*)&scf[prow][0]
                                          + t0 + ks * 32 + fk);
                po[mi] = __builtin_amdgcn_mfma_f32_16x16x32_bf16(pf, vf, po[mi], 0, 0, 0);
            }
        }
    }

#pragma unroll
    for (int mi = 0; mi < 2; ++mi)
#pragma unroll
        for (int r = 0; r < 4; ++r) {
            const int row = mi * 16 + (lane >> 4) * 4 + r;
            if (row < KPS)
                outb[((size_t)b * NROWS + s0 * KPS + row) * DDIM
                     + h * HD + w * 16 + frow] = f2bf(po[mi][r] * invb[row]);
        }
}

// ---------------------------------------------------------------------------
// LayerNorm fp32 -> bf16. One wave per row.
// ---------------------------------------------------------------------------
__global__ __launch_bounds__(256) void ln_kernel(
    const float* __restrict__ f, const float* __restrict__ g,
    const float* __restrict__ bt, unsigned short* __restrict__ o)
{
    const int row = blockIdx.x * 4 + (threadIdx.x >> 6);
    const int lane = threadIdx.x & 63;
    const float* fr = f + (size_t)row * DDIM;
    float xv[8];
    float s = 0.f;
#pragma unroll
    for (int i = 0; i < 8; ++i) { xv[i] = fr[lane + i * 64]; s += xv[i]; }
#pragma unroll
    for (int off = 32; off; off >>= 1) s += __shfl_xor(s, off, 64);
    const float mu = s * (1.0f / DDIM);
    float var = 0.f;
#pragma unroll
    for (int i = 0; i < 8; ++i) { const float d0 = xv[i] - mu; var += d0 * d0; }
#pragma unroll
    for (int off = 32; off; off >>= 1) var += __shfl_xor(var, off, 64);
    const float rs = rsqrtf(var * (1.0f / DDIM) + 1e-5f);
#pragma unroll
    for (int i = 0; i < 8; ++i) {
        const int d0 = lane + i * 64;
        o[(size_t)row * DDIM + d0] = f2bf((xv[i] - mu) * rs * g[d0] + bt[d0]);
    }
}

// ---------------------------------------------------------------------------
// Final head.
// ---------------------------------------------------------------------------
__global__ __launch_bounds__(256) void w2_kernel(
    const unsigned short* __restrict__ h, const float* __restrict__ W2,
    const float* __restrict__ b2, float* __restrict__ out)
{
    const int row = blockIdx.x * 4 + (threadIdx.x >> 6);
    const int lane = threadIdx.x & 63;
    float s = 0.f;
#pragma unroll
    for (int i = 0; i < 8; ++i) {
        const int d = lane + i * 64;
        s += bf2f(h[(size_t)row * DDIM + d]) * W2[d];
    }
#pragma unroll
    for (int off = 32; off; off >>= 1) s += __shfl_xor(s, off, 64);
    if (lane == 0) out[row] = s + b2[0];
}

// ---------------------------------------------------------------------------
extern "C" void kernel_launch(void* const* d_in, const int* in_sizes, int n_in,
                              void* d_out, int out_size, void* d_ws, size_t ws_size,
                              hipStream_t stream)
{
    const float* item = (const float*)d_in[0];
    const float* user = (const float*)d_in[1];
    const int*   resp = (const int*)d_in[2];
    const float* Wq = (const float*)d_in[3];  const float* bq = (const float*)d_in[4];
    const float* Wk = (const float*)d_in[5];  const float* bk = (const float*)d_in[6];
    const float* Wv = (const float*)d_in[7];  const float* bv = (const float*)d_in[8];
    const float* Wo = (const float*)d_in[9];  const float* bo = (const float*)d_in[10];
    const float* lng = (const float*)d_in[11]; const float* lnb = (const float*)d_in[12];
    const float* W1 = (const float*)d_in[13]; const float* b1 = (const float*)d_in[14];
    const float* W2 = (const float*)d_in[15]; const float* b2 = (const float*)d_in[16];
    float* out = (float*)d_out;

    char* p = (char*)d_ws;
    auto alloc = [&](size_t bytes) { char* r = p; p += (bytes + 255) & ~(size_t)255; return r; };
    const size_t NITEM = (size_t)BATCH * NROWS * EDIM;
    const size_t NW    = (size_t)DDIM * DDIM;
    const size_t NQKV  = (size_t)BATCH * HEADS * LFULL * HD;
    const size_t NMD   = (size_t)MTOT * DDIM;

    unsigned short* itemb = (unsigned short*)alloc(NITEM * 2);
    unsigned short* Wqb = (unsigned short*)alloc(NW * 2);
    unsigned short* Wkb = (unsigned short*)alloc(NW * 2);
    unsigned short* Wvb = (unsigned short*)alloc(NW * 2);
    unsigned short* Wob = (unsigned short*)alloc(NW * 2);
    unsigned short* W1b = (unsigned short*)alloc(NW * 2);
    unsigned short* qb  = (unsigned short*)alloc(NQKV * 2);
    unsigned short* kb  = (unsigned short*)alloc(NQKV * 2);
    unsigned short* vb  = (unsigned short*)alloc(NQKV * 2);
    unsigned short* aob = (unsigned short*)alloc(NMD * 2);
    unsigned short* hb  = (unsigned short*)alloc(NMD * 2);
    float* fbuf = (float*)alloc(NMD * 4);
    float* ubq  = (float*)alloc((size_t)BATCH * DDIM * 4);
    float* ubk  = (float*)alloc((size_t)BATCH * DDIM * 4);
    float* ubv  = (float*)alloc((size_t)BATCH * DDIM * 4);

    cvt_kernel<<<dim3((NITEM / 4 + 255) / 256), 256, 0, stream>>>(item, itemb, NITEM / 4);
    Cvt5 c5;
    c5.s[0] = Wq; c5.s[1] = Wk; c5.s[2] = Wv; c5.s[3] = Wo; c5.s[4] = W1;
    c5.d[0] = Wqb; c5.d[1] = Wkb; c5.d[2] = Wvb; c5.d[3] = Wob; c5.d[4] = W1b;
    cvt5_kernel<<<dim3(NW / 4 / 256, 5), 256, 0, stream>>>(c5, NW / 4);

    user_bias_kernel<<<dim3(BATCH, 3), 256, 0, stream>>>(
        user, Wq, bq, Wk, bk, Wv, bv, ubq, ubk, ubv, qb, kb, vb);

    dim3 gq(DDIM / 128, MTOT / 128, 3);
    gemm_qkv<<<gq, 256, 0, stream>>>(itemb, Wqb, Wkb, Wvb, ubq, ubk, ubv, qb, kb, vb);

    attn_mfma<<<dim3(SLATES, HEADS, BATCH), 256, 0, stream>>>(qb, kb, vb, resp, aob);

    dim3 gg(DDIM / 128, MTOT / 128);
    gemm_bf16<1><<<gg, 256, 0, stream>>>(aob, Wob, bo, fbuf);
    ln_kernel<<<dim3(MTOT / 4), 256, 0, stream>>>(fbuf, lng, lnb, aob);
    gemm_bf16<2><<<gg, 256, 0, stream>>>(aob, W1b, b1, hb);
    w2_kernel<<<dim3(MTOT / 4), 256, 0, stream>>>(hb, W2, b2, out);
}